// Round 7
// baseline (330.812 us; speedup 1.0000x reference)
//
#include <hip/hip_runtime.h>

// ProbabilityMatrix: 4x row-histogram of per-patch popcounts, normalized.
// ws layout (ints) == out layout (floats), flat concat:
//   box0 [16][16] @ 0, box1 [16][64] @ 256, box2 [16][16] @ 1280, box3 [16][64] @ 1536

#define P_PATCH 32768
#define B_ROWS  16

// DPP-based partial add (pure VALU). quad_perm[1,0,3,2]=0xB1 (xor1),
// quad_perm[2,3,0,1]=0x4E (xor2), row_ror:4=0x124, row_ror:8=0x128.
template <int CTRL>
__device__ __forceinline__ float dpp_add(float s) {
    int t = __builtin_amdgcn_update_dpp(0, __float_as_int(s), CTRL, 0xF, 0xF, true);
    return s + __int_as_float(t);
}

// Patch sum (all lanes of the FV-group get it) -> packed-u8 register bincount.
// Lane with m = lane&(FV-1) counts only bins [4m, 4m+4), one byte each.
// bin == S2 (popcount 16/64) is dropped automatically: S2>>2 == FV > FV-1 >= m.
template <int FV>
__device__ __forceinline__ void count_f4(float4 v, int m, unsigned& cnt) {
    float x = (v.x + v.y) + (v.z + v.w);
    x = dpp_add<0xB1>(x);
    x = dpp_add<0x4E>(x);                 // quad sum
    if (FV == 16) {
        x = dpp_add<0x124>(x);
        x = dpp_add<0x128>(x);            // 16-lane sum, all lanes
    }
    int bin = (int)(x + 0.5f);            // exact: sum of 0/1 floats
    cnt += ((bin >> 2) == m) ? (1u << ((bin & 3) << 3)) : 0u;
}

// FV = float4 per patch (4 or 16). Blocks partitioned BY ROW: row is
// block-uniform, per-thread packed counters are per-row. Hot loop: coalesced
// named-register loads + VALU only (no LDS ops).
template <int FV, int BPR>   // BPR = blocks per row
__device__ __forceinline__ void hist_box(const float4* __restrict__ in,
                                         int* __restrict__ gcounts,
                                         int block_rank,
                                         int* ldsHist) {
    constexpr int S2     = FV * 4;
    constexpr int U      = 8;                      // float4 per thread per tile
    constexpr int ROW_F4 = P_PATCH * FV;           // float4 per row (2^17 / 2^19)
    constexpr int TPR    = ROW_F4 / (256 * U);     // tiles per row (64 / 256)
    const int tid = (int)threadIdx.x;

    const int row = block_rank / BPR;              // constant divisor -> shifts
    const int br  = block_rank % BPR;
    const float4* rowbase = in + (size_t)row * ROW_F4;

    for (int i = tid; i < S2; i += 256) ldsHist[i] = 0;
    __syncthreads();

    const int m = tid & (FV - 1);
    unsigned cnt = 0;                              // 4 packed u8 counters, bins 4m..4m+3

    for (int t = br; t < TPR; t += BPR) {          // exactly TPR/BPR = 4 iters
        const float4* p = rowbase + t * (256 * U) + tid;
        float4 v0 = p[0 * 256], v1 = p[1 * 256], v2 = p[2 * 256], v3 = p[3 * 256];
        float4 v4 = p[4 * 256], v5 = p[5 * 256], v6 = p[6 * 256], v7 = p[7 * 256];
        count_f4<FV>(v0, m, cnt);
        count_f4<FV>(v1, m, cnt);
        count_f4<FV>(v2, m, cnt);
        count_f4<FV>(v3, m, cnt);
        count_f4<FV>(v4, m, cnt);
        count_f4<FV>(v5, m, cnt);
        count_f4<FV>(v6, m, cnt);
        count_f4<FV>(v7, m, cnt);
    }

    // one-time merge: unpack u8 counters into the block's single-row histogram
    atomicAdd(&ldsHist[4 * m + 0], (int)( cnt        & 0xffu));
    atomicAdd(&ldsHist[4 * m + 1], (int)((cnt >>  8) & 0xffu));
    atomicAdd(&ldsHist[4 * m + 2], (int)((cnt >> 16) & 0xffu));
    atomicAdd(&ldsHist[4 * m + 3], (int)( cnt >> 24));
    __syncthreads();

    for (int i = tid; i < S2; i += 256) {
        int c = ldsHist[i];
        if (c) atomicAdd(&gcounts[row * S2 + i], c);
    }
}

#define NB0 256    // 16 blocks/row, 64 tiles/row -> 4 tiles/block
#define NB1 1024   // 64 blocks/row, 256 tiles/row -> 4 tiles/block
// grid = 2*(NB0+NB1) = 2560 blocks; per-thread work balanced (32 float4 each)

__global__ __launch_bounds__(256) void hist_kernel(const float4* __restrict__ in0,
                                                   const float4* __restrict__ in1,
                                                   const float4* __restrict__ in2,
                                                   const float4* __restrict__ in3,
                                                   int* __restrict__ ws) {
    __shared__ int ldsHist[64];           // 256 B, worst case S2=64
    const int bid = blockIdx.x;
    if (bid < NB0)              hist_box<4,  16>(in0, ws + 0,    bid,               ldsHist);
    else if (bid < NB0 + NB1)   hist_box<16, 64>(in1, ws + 256,  bid - NB0,         ldsHist);
    else if (bid < 2*NB0 + NB1) hist_box<4,  16>(in2, ws + 1280, bid - NB0 - NB1,   ldsHist);
    else                        hist_box<16, 64>(in3, ws + 1536, bid - 2*NB0 - NB1, ldsHist);
}

// one 64-lane wave per (box,row): out[v] = counts[v] / rowsum
__global__ __launch_bounds__(64) void norm_kernel(const int* __restrict__ ws,
                                                  float* __restrict__ out) {
    const int row  = blockIdx.x;      // 0..63
    const int lane = threadIdx.x;     // 0..63
    const int box  = row >> 4;
    const int r    = row & 15;
    const int bins = (box & 1) ? 64 : 16;
    int off = (box == 0) ? 0 : (box == 1) ? 256 : (box == 2) ? 1280 : 1536;
    off += r * bins;

    int c = (lane < bins) ? ws[off + lane] : 0;
    int total = c;
#pragma unroll
    for (int d = 32; d > 0; d >>= 1) total += __shfl_down(total, d);
    total = __shfl(total, 0);

    if (lane < bins) out[off + lane] = (float)c / (float)total;
}

extern "C" void kernel_launch(void* const* d_in, const int* in_sizes, int n_in,
                              void* d_out, int out_size, void* d_ws, size_t ws_size,
                              hipStream_t stream) {
    const float4* in0 = (const float4*)d_in[0];  // cd0_box0 [16,32768,4,4]
    const float4* in1 = (const float4*)d_in[1];  // cd0_box1 [16,32768,8,8]
    const float4* in2 = (const float4*)d_in[2];  // cd1_box0 [16,32768,4,4]
    const float4* in3 = (const float4*)d_in[3];  // cd1_box1 [16,32768,8,8]
    int* ws = (int*)d_ws;

    hipMemsetAsync(ws, 0, 2560 * sizeof(int), stream);
    hist_kernel<<<2 * (NB0 + NB1), 256, 0, stream>>>(in0, in1, in2, in3, ws);
    norm_kernel<<<64, 64, 0, stream>>>(ws, (float*)d_out);
}

// Round 8
// 292.736 us; speedup vs baseline: 1.1301x; 1.1301x over previous
//
#include <hip/hip_runtime.h>

// ProbabilityMatrix: 4x row-histogram of per-patch popcounts, normalized.
// ws layout (ints) == out layout (floats), flat concat:
//   box0 [16][16] @ 0, box1 [16][64] @ 256, box2 [16][16] @ 1280, box3 [16][64] @ 1536

#define P_PATCH 32768
#define B_ROWS  16

typedef float f4 __attribute__((ext_vector_type(4)));   // builtin-compatible float4

// DPP-based partial add (pure VALU). quad_perm[1,0,3,2]=0xB1 (xor1),
// quad_perm[2,3,0,1]=0x4E (xor2), row_ror:4=0x124, row_ror:8=0x128.
template <int CTRL>
__device__ __forceinline__ float dpp_add(float s) {
    int t = __builtin_amdgcn_update_dpp(0, __float_as_int(s), CTRL, 0xF, 0xF, true);
    return s + __int_as_float(t);
}

// Patch sum (all lanes of the FV-group get it) -> packed-u8 register bincount.
// Lane with m = lane&(FV-1) counts only bins [4m, 4m+4), one byte each.
// bin == S2 (popcount 16/64) is dropped automatically: S2>>2 == FV > FV-1 >= m.
template <int FV>
__device__ __forceinline__ void count_f4(f4 v, int m, unsigned& cnt) {
    float x = (v.x + v.y) + (v.z + v.w);
    x = dpp_add<0xB1>(x);
    x = dpp_add<0x4E>(x);                 // quad sum
    if (FV == 16) {
        x = dpp_add<0x124>(x);
        x = dpp_add<0x128>(x);            // 16-lane sum, all lanes
    }
    int bin = (int)(x + 0.5f);            // exact: sum of 0/1 floats
    cnt += ((bin >> 2) == m) ? (1u << ((bin & 3) << 3)) : 0u;
}

// FV = float4 per patch (4 or 16). Blocks partitioned BY ROW (row block-uniform).
// Hot loop: coalesced NON-TEMPORAL loads + VALU only (no LDS ops, no cache alloc).
template <int FV, int BPR>   // BPR = blocks per row
__device__ __forceinline__ void hist_box(const f4* __restrict__ in,
                                         int* __restrict__ gcounts,
                                         int block_rank,
                                         int* ldsHist) {
    constexpr int S2     = FV * 4;
    constexpr int U      = 8;                      // f4 per thread per tile
    constexpr int ROW_F4 = P_PATCH * FV;           // f4 per row (2^17 / 2^19)
    constexpr int TPR    = ROW_F4 / (256 * U);     // tiles per row (64 / 256)
    const int tid = (int)threadIdx.x;

    const int row = block_rank / BPR;              // constant divisor -> shifts
    const int br  = block_rank % BPR;
    const f4* rowbase = in + (size_t)row * ROW_F4;

    for (int i = tid; i < S2; i += 256) ldsHist[i] = 0;
    __syncthreads();

    const int m = tid & (FV - 1);
    unsigned cnt = 0;                              // 4 packed u8 counters, bins 4m..4m+3

    for (int t = br; t < TPR; t += BPR) {          // exactly TPR/BPR = 4 iters
        const f4* p = rowbase + t * (256 * U) + tid;
        f4 v0 = __builtin_nontemporal_load(p + 0 * 256);
        f4 v1 = __builtin_nontemporal_load(p + 1 * 256);
        f4 v2 = __builtin_nontemporal_load(p + 2 * 256);
        f4 v3 = __builtin_nontemporal_load(p + 3 * 256);
        f4 v4 = __builtin_nontemporal_load(p + 4 * 256);
        f4 v5 = __builtin_nontemporal_load(p + 5 * 256);
        f4 v6 = __builtin_nontemporal_load(p + 6 * 256);
        f4 v7 = __builtin_nontemporal_load(p + 7 * 256);
        count_f4<FV>(v0, m, cnt);
        count_f4<FV>(v1, m, cnt);
        count_f4<FV>(v2, m, cnt);
        count_f4<FV>(v3, m, cnt);
        count_f4<FV>(v4, m, cnt);
        count_f4<FV>(v5, m, cnt);
        count_f4<FV>(v6, m, cnt);
        count_f4<FV>(v7, m, cnt);
    }

    // one-time merge: unpack u8 counters into the block's single-row histogram
    atomicAdd(&ldsHist[4 * m + 0], (int)( cnt        & 0xffu));
    atomicAdd(&ldsHist[4 * m + 1], (int)((cnt >>  8) & 0xffu));
    atomicAdd(&ldsHist[4 * m + 2], (int)((cnt >> 16) & 0xffu));
    atomicAdd(&ldsHist[4 * m + 3], (int)( cnt >> 24));
    __syncthreads();

    for (int i = tid; i < S2; i += 256) {
        int c = ldsHist[i];
        if (c) atomicAdd(&gcounts[row * S2 + i], c);
    }
}

#define NB0 256    // 16 blocks/row, 64 tiles/row -> 4 tiles/block
#define NB1 1024   // 64 blocks/row, 256 tiles/row -> 4 tiles/block
// grid = 2*(NB0+NB1) = 2560 blocks; per-thread work balanced (32 f4 each)

__global__ __launch_bounds__(256) void hist_kernel(const f4* __restrict__ in0,
                                                   const f4* __restrict__ in1,
                                                   const f4* __restrict__ in2,
                                                   const f4* __restrict__ in3,
                                                   int* __restrict__ ws) {
    __shared__ int ldsHist[64];           // 256 B, worst case S2=64
    const int bid = blockIdx.x;
    if (bid < NB0)              hist_box<4,  16>(in0, ws + 0,    bid,               ldsHist);
    else if (bid < NB0 + NB1)   hist_box<16, 64>(in1, ws + 256,  bid - NB0,         ldsHist);
    else if (bid < 2*NB0 + NB1) hist_box<4,  16>(in2, ws + 1280, bid - NB0 - NB1,   ldsHist);
    else                        hist_box<16, 64>(in3, ws + 1536, bid - 2*NB0 - NB1, ldsHist);
}

// one 64-lane wave per (box,row): out[v] = counts[v] / rowsum
__global__ __launch_bounds__(64) void norm_kernel(const int* __restrict__ ws,
                                                  float* __restrict__ out) {
    const int row  = blockIdx.x;      // 0..63
    const int lane = threadIdx.x;     // 0..63
    const int box  = row >> 4;
    const int r    = row & 15;
    const int bins = (box & 1) ? 64 : 16;
    int off = (box == 0) ? 0 : (box == 1) ? 256 : (box == 2) ? 1280 : 1536;
    off += r * bins;

    int c = (lane < bins) ? ws[off + lane] : 0;
    int total = c;
#pragma unroll
    for (int d = 32; d > 0; d >>= 1) total += __shfl_down(total, d);
    total = __shfl(total, 0);

    if (lane < bins) out[off + lane] = (float)c / (float)total;
}

extern "C" void kernel_launch(void* const* d_in, const int* in_sizes, int n_in,
                              void* d_out, int out_size, void* d_ws, size_t ws_size,
                              hipStream_t stream) {
    const f4* in0 = (const f4*)d_in[0];  // cd0_box0 [16,32768,4,4]
    const f4* in1 = (const f4*)d_in[1];  // cd0_box1 [16,32768,8,8]
    const f4* in2 = (const f4*)d_in[2];  // cd1_box0 [16,32768,4,4]
    const f4* in3 = (const f4*)d_in[3];  // cd1_box1 [16,32768,8,8]
    int* ws = (int*)d_ws;

    hipMemsetAsync(ws, 0, 2560 * sizeof(int), stream);
    hist_kernel<<<2 * (NB0 + NB1), 256, 0, stream>>>(in0, in1, in2, in3, ws);
    norm_kernel<<<64, 64, 0, stream>>>(ws, (float*)d_out);
}

// Round 9
// 290.901 us; speedup vs baseline: 1.1372x; 1.0063x over previous
//
#include <hip/hip_runtime.h>

// ProbabilityMatrix: 4x row-histogram of per-patch popcounts, normalized.
// ws layout (ints) == out layout (floats), flat concat:
//   box0 [16][16] @ 0, box1 [16][64] @ 256, box2 [16][16] @ 1280, box3 [16][64] @ 1536

#define P_PATCH 32768
#define B_ROWS  16

typedef float f4 __attribute__((ext_vector_type(4)));   // builtin-compatible float4

// DPP-based partial add (pure VALU). quad_perm[1,0,3,2]=0xB1 (xor1),
// quad_perm[2,3,0,1]=0x4E (xor2), row_ror:4=0x124, row_ror:8=0x128.
template <int CTRL>
__device__ __forceinline__ float dpp_add(float s) {
    int t = __builtin_amdgcn_update_dpp(0, __float_as_int(s), CTRL, 0xF, 0xF, true);
    return s + __int_as_float(t);
}

// Patch sum (all lanes of the FV-group get it) -> packed-u8 register bincount.
// Lane with m = lane&(FV-1) counts only bins [4m, 4m+4), one byte each.
// bin == S2 (popcount 16/64) is dropped automatically: S2>>2 == FV > FV-1 >= m.
template <int FV>
__device__ __forceinline__ void count_f4(f4 v, int m, unsigned& cnt) {
    float x = (v.x + v.y) + (v.z + v.w);
    x = dpp_add<0xB1>(x);
    x = dpp_add<0x4E>(x);                 // quad sum
    if (FV == 16) {
        x = dpp_add<0x124>(x);
        x = dpp_add<0x128>(x);            // 16-lane sum, all lanes
    }
    int bin = (int)(x + 0.5f);            // exact: sum of 0/1 floats
    cnt += ((bin >> 2) == m) ? (1u << ((bin & 3) << 3)) : 0u;
}

// FV = float4 per patch (4 or 16). ONE tile per block (no loop): each thread
// issues all 32 nt loads back-to-back (32 KB in flight per wave), then drains
// through DPP chains with staggered vmcnt waits. Row is block-uniform.
template <int FV, int BPR>   // BPR = blocks per row
__device__ __forceinline__ void hist_box(const f4* __restrict__ in,
                                         int* __restrict__ gcounts,
                                         int block_rank,
                                         int* ldsHist) {
    constexpr int S2     = FV * 4;
    constexpr int U      = 32;                     // f4 per thread (whole share)
    constexpr int ROW_F4 = P_PATCH * FV;           // f4 per row (2^17 / 2^19)
    static_assert(ROW_F4 / (256 * U) == BPR, "one tile per block");
    const int tid = (int)threadIdx.x;

    const int row = block_rank / BPR;              // constant divisor -> shifts
    const int br  = block_rank % BPR;
    const f4* p   = in + (size_t)row * ROW_F4 + br * (256 * U) + tid;

    for (int i = tid; i < S2; i += 256) ldsHist[i] = 0;
    __syncthreads();

    const int m = tid & (FV - 1);
    unsigned cnt = 0;                              // 4 packed u8 counters, bins 4m..4m+3

    f4 v[U];
#pragma unroll
    for (int k = 0; k < U; ++k)                    // 32 nt loads, all in flight
        v[k] = __builtin_nontemporal_load(p + k * 256);
#pragma unroll
    for (int k = 0; k < U; ++k)
        count_f4<FV>(v[k], m, cnt);

    // one-time merge: unpack u8 counters into the block's single-row histogram
    atomicAdd(&ldsHist[4 * m + 0], (int)( cnt        & 0xffu));
    atomicAdd(&ldsHist[4 * m + 1], (int)((cnt >>  8) & 0xffu));
    atomicAdd(&ldsHist[4 * m + 2], (int)((cnt >> 16) & 0xffu));
    atomicAdd(&ldsHist[4 * m + 3], (int)( cnt >> 24));
    __syncthreads();

    for (int i = tid; i < S2; i += 256) {
        int c = ldsHist[i];
        if (c) atomicAdd(&gcounts[row * S2 + i], c);
    }
}

#define NB0 256    // 16 blocks/row x 16 rows (tile = 8192 f4, 16 tiles/row)
#define NB1 1024   // 64 blocks/row x 16 rows
// grid = 2*(NB0+NB1) = 2560 blocks, exactly one 128 KB tile each; zero tail

__global__ __launch_bounds__(256) void hist_kernel(const f4* __restrict__ in0,
                                                   const f4* __restrict__ in1,
                                                   const f4* __restrict__ in2,
                                                   const f4* __restrict__ in3,
                                                   int* __restrict__ ws) {
    __shared__ int ldsHist[64];           // 256 B, worst case S2=64
    const int bid = blockIdx.x;
    if (bid < NB0)              hist_box<4,  16>(in0, ws + 0,    bid,               ldsHist);
    else if (bid < NB0 + NB1)   hist_box<16, 64>(in1, ws + 256,  bid - NB0,         ldsHist);
    else if (bid < 2*NB0 + NB1) hist_box<4,  16>(in2, ws + 1280, bid - NB0 - NB1,   ldsHist);
    else                        hist_box<16, 64>(in3, ws + 1536, bid - 2*NB0 - NB1, ldsHist);
}

// one 64-lane wave per (box,row): out[v] = counts[v] / rowsum
__global__ __launch_bounds__(64) void norm_kernel(const int* __restrict__ ws,
                                                  float* __restrict__ out) {
    const int row  = blockIdx.x;      // 0..63
    const int lane = threadIdx.x;     // 0..63
    const int box  = row >> 4;
    const int r    = row & 15;
    const int bins = (box & 1) ? 64 : 16;
    int off = (box == 0) ? 0 : (box == 1) ? 256 : (box == 2) ? 1280 : 1536;
    off += r * bins;

    int c = (lane < bins) ? ws[off + lane] : 0;
    int total = c;
#pragma unroll
    for (int d = 32; d > 0; d >>= 1) total += __shfl_down(total, d);
    total = __shfl(total, 0);

    if (lane < bins) out[off + lane] = (float)c / (float)total;
}

extern "C" void kernel_launch(void* const* d_in, const int* in_sizes, int n_in,
                              void* d_out, int out_size, void* d_ws, size_t ws_size,
                              hipStream_t stream) {
    const f4* in0 = (const f4*)d_in[0];  // cd0_box0 [16,32768,4,4]
    const f4* in1 = (const f4*)d_in[1];  // cd0_box1 [16,32768,8,8]
    const f4* in2 = (const f4*)d_in[2];  // cd1_box0 [16,32768,4,4]
    const f4* in3 = (const f4*)d_in[3];  // cd1_box1 [16,32768,8,8]
    int* ws = (int*)d_ws;

    hipMemsetAsync(ws, 0, 2560 * sizeof(int), stream);
    hist_kernel<<<2 * (NB0 + NB1), 256, 0, stream>>>(in0, in1, in2, in3, ws);
    norm_kernel<<<64, 64, 0, stream>>>(ws, (float*)d_out);
}